// Round 2
// baseline (4396.758 us; speedup 1.0000x reference)
//
#include <hip/hip_runtime.h>
#include <math.h>

#define B_ 2
#define N_ 2048
#define DIM_ 1024
#define HEADS_ 8
#define DH_ 64
#define DEPTH_ 4
#define VOCAB_ 32000
#define FF_ 4096
#define INNER_ 512
#define M_ (B_*N_)
#define QKVN_ 640

typedef __bf16 bf16x8 __attribute__((ext_vector_type(8)));
typedef short short8 __attribute__((ext_vector_type(8)));
typedef float f32x4 __attribute__((ext_vector_type(4)));

__device__ __forceinline__ ushort f2bf(float f) {
  union { float f; unsigned u; } v; v.f = f;
  unsigned r = v.u + 0x7fffu + ((v.u >> 16) & 1u);
  return (ushort)(r >> 16);
}

// ---------- transpose fp32 (R,C) -> bf16 (C,R) ----------
__global__ void k_transpose_bf16(const float* __restrict__ in, ushort* __restrict__ out,
                                 int R, int C) {
  __shared__ float tile[32][33];
  int c0 = blockIdx.x * 32, r0 = blockIdx.y * 32;
  int tx = threadIdx.x, ty = threadIdx.y;
  for (int rr = ty; rr < 32; rr += 8)
    tile[rr][tx] = in[(size_t)(r0 + rr) * C + c0 + tx];
  __syncthreads();
  for (int rr = ty; rr < 32; rr += 8)
    out[(size_t)(c0 + rr) * R + r0 + tx] = f2bf(tile[tx][rr]);
}

// ---------- relative-position bias table: [l][h][n] ----------
__global__ void k_biastab(const float* __restrict__ rel_emb, float* __restrict__ tab) {
  int idx = blockIdx.x * 256 + threadIdx.x;
  if (idx >= DEPTH_ * HEADS_ * N_) return;
  int n = idx & (N_ - 1);
  int h = (idx >> 11) & (HEADS_ - 1);
  int l = idx >> 14;
  int bucket;
  if (n < 16) {
    bucket = n;
  } else {
    float nf = (float)n;
    int v = (int)(logf(nf * (1.0f / 16.0f)) / 2.0794415416798357f * 16.0f);
    bucket = 16 + v;
    if (bucket > 31) bucket = 31;
  }
  tab[idx] = rel_emb[(l * 32 + bucket) * HEADS_ + h] * 8.0f;
}

// ---------- embedding ----------
__global__ void k_embed(const int* __restrict__ tok, const float* __restrict__ emb,
                        float* __restrict__ x) {
  int row = blockIdx.x;
  int t = tok[row];
  const float4* src = (const float4*)(emb + (size_t)t * DIM_);
  float4* dst = (float4*)(x + (size_t)row * DIM_);
  dst[threadIdx.x] = src[threadIdx.x];
}

// ---------- layernorm (fp32 in) -> bf16 out ----------
__global__ __launch_bounds__(256) void k_ln(const float* __restrict__ x,
                                            const float* __restrict__ g,
                                            const float* __restrict__ b,
                                            ushort* __restrict__ out) {
  int row = blockIdx.x;
  const float* xr = x + (size_t)row * DIM_;
  int t = threadIdx.x;
  float4 v = *(const float4*)(xr + t * 4);
  float s = v.x + v.y + v.z + v.w;
#pragma unroll
  for (int off = 32; off; off >>= 1) s += __shfl_xor(s, off);
  __shared__ float red[4], red2[4];
  int w = t >> 6;
  if ((t & 63) == 0) red[w] = s;
  __syncthreads();
  float mu = (red[0] + red[1] + red[2] + red[3]) * (1.0f / DIM_);
  float d0 = v.x - mu, d1 = v.y - mu, d2 = v.z - mu, d3 = v.w - mu;
  float sq = d0 * d0 + d1 * d1 + d2 * d2 + d3 * d3;
#pragma unroll
  for (int off = 32; off; off >>= 1) sq += __shfl_xor(sq, off);
  if ((t & 63) == 0) red2[w] = sq;
  __syncthreads();
  float var = (red2[0] + red2[1] + red2[2] + red2[3]) * (1.0f / DIM_);
  float rinv = 1.0f / sqrtf(var + 1e-5f);
  int c = t * 4;
  ushort4 o;
  o.x = f2bf(d0 * rinv * g[c] + b[c]);
  o.y = f2bf(d1 * rinv * g[c + 1] + b[c + 1]);
  o.z = f2bf(d2 * rinv * g[c + 2] + b[c + 2]);
  o.w = f2bf(d3 * rinv * g[c + 3] + b[c + 3]);
  *(ushort4*)(out + (size_t)row * DIM_ + c) = o;
}

// ---------- k transpose: kT[b][d][n] = qkv[b,n,512+d] ----------
__global__ void k_kt(const float* __restrict__ qkv, float* __restrict__ kT) {
  int idx = blockIdx.x * 256 + threadIdx.x;  // < B*64*N
  int b = idx >> 17;
  int r = idx & 131071;
  int d = r >> 11;
  int n = r & 2047;
  kT[idx] = qkv[((size_t)(b * N_ + n)) * QKVN_ + INNER_ + d];
}

// ---------- GEMM: C[M,N] = A[M,K](bf16) * Bt[N,K](bf16)^T, fp32 acc ----------
// EPI: 0 = Cf=acc; 1 = Cf=acc+bias; 2 = Cf=acc+bias+res (in-place ok);
//      3 = Cb=bf16(gelu(acc+bias))
template<int EPI>
__global__ __launch_bounds__(256) void k_gemm(const ushort* __restrict__ A,
                                              const ushort* __restrict__ Bt,
                                              const float* __restrict__ bias,
                                              const float* res,
                                              float* Cf, ushort* Cb,
                                              int M, int N, int K) {
  __shared__ ushort As[128][40];
  __shared__ ushort Bs[128][40];
  int t = threadIdx.x;
  int wave = t >> 6, lane = t & 63;
  int wr = (wave >> 1) * 64, wc = (wave & 1) * 64;
  int brow = blockIdx.y * 128, bcol = blockIdx.x * 128;
  int lr = lane & 15, kk = (lane >> 4) * 8;
  f32x4 acc[4][4] = {};

  int sr = t >> 2;
  int sk = (t & 3) * 8;
  const ushort* Ap = A + (size_t)(brow + sr) * K + sk;
  const ushort* Bp = Bt + (size_t)(bcol + sr) * K + sk;

  for (int k0 = 0; k0 < K; k0 += 32) {
    short8 a0 = *(const short8*)Ap;
    short8 a1 = *(const short8*)(Ap + (size_t)64 * K);
    short8 b0 = *(const short8*)Bp;
    short8 b1 = *(const short8*)(Bp + (size_t)64 * K);
    Ap += 32; Bp += 32;
    __syncthreads();
    *(short8*)&As[sr][sk] = a0;
    *(short8*)&As[sr + 64][sk] = a1;
    *(short8*)&Bs[sr][sk] = b0;
    *(short8*)&Bs[sr + 64][sk] = b1;
    __syncthreads();
    bf16x8 af[4], bfv[4];
#pragma unroll
    for (int mi = 0; mi < 4; ++mi)
      af[mi] = __builtin_bit_cast(bf16x8, *(const short8*)&As[wr + mi * 16 + lr][kk]);
#pragma unroll
    for (int ni = 0; ni < 4; ++ni)
      bfv[ni] = __builtin_bit_cast(bf16x8, *(const short8*)&Bs[wc + ni * 16 + lr][kk]);
#pragma unroll
    for (int mi = 0; mi < 4; ++mi)
#pragma unroll
      for (int ni = 0; ni < 4; ++ni)
        acc[mi][ni] = __builtin_amdgcn_mfma_f32_16x16x32_bf16(af[mi], bfv[ni], acc[mi][ni], 0, 0, 0);
  }

  int rbase = brow + wr + ((lane >> 4) << 2);
  int cbase = bcol + wc + lr;
#pragma unroll
  for (int mi = 0; mi < 4; ++mi) {
#pragma unroll
    for (int ni = 0; ni < 4; ++ni) {
      int col = cbase + ni * 16;
      float bv = 0.f;
      if constexpr (EPI >= 1) bv = bias[col];
#pragma unroll
      for (int j = 0; j < 4; ++j) {
        int row = rbase + mi * 16 + j;
        size_t idx = (size_t)row * N + col;
        float v = acc[mi][ni][j];
        if constexpr (EPI == 0) Cf[idx] = v;
        if constexpr (EPI == 1) Cf[idx] = v + bv;
        if constexpr (EPI == 2) Cf[idx] = v + bv + res[idx];
        if constexpr (EPI == 3) {
          float u = v + bv;
          Cb[idx] = f2bf(0.5f * u * (1.0f + erff(u * 0.70710678f)));
        }
      }
    }
  }
}

// ---------- flash attention (online softmax), causal + rel-bias ----------
// grid (32, B*H), 256 threads. Block x handles 32-row chunks {x, 63-x} (load balance).
__global__ __launch_bounds__(256) void k_attn(const float* __restrict__ qkv,
                                              const float* __restrict__ kT,
                                              const float* __restrict__ btab,
                                              ushort* __restrict__ o) {
  int bh = blockIdx.y;
  int b = bh >> 3, h = bh & 7;
  int t = threadIdx.x, w = t >> 6, lane = t & 63;
  __shared__ float Kl[64][64];   // [d][j]
  __shared__ float Vl[64][64];   // [j][d]
  __shared__ float Ql[32][64];   // [r][d]
  __shared__ float accs[4][8][64];
  __shared__ float ps[4][64];
  __shared__ float m_s[4][8], l_s[4][8];
  const float* bias_h = btab + (size_t)h * N_;

  for (int pass = 0; pass < 2; ++pass) {
    int chunk = pass ? (63 - (int)blockIdx.x) : (int)blockIdx.x;
    int i0 = chunk * 32;
    __syncthreads();
    // stage Q (scaled)
    for (int p = 0; p < 2; ++p) {
      int r = (t >> 4) + p * 16;
      int d4 = (t & 15) * 4;
      float4 qv = *(const float4*)(qkv + ((size_t)(b * N_ + i0 + r)) * QKVN_ + h * DH_ + d4);
      qv.x *= 0.125f; qv.y *= 0.125f; qv.z *= 0.125f; qv.w *= 0.125f;
      *(float4*)(&Ql[r][d4]) = qv;
    }
#pragma unroll
    for (int r = 0; r < 8; ++r) accs[w][r][lane] = 0.f;
    if (lane < 8) { m_s[w][lane] = -1e30f; l_s[w][lane] = 0.f; }
    int ntiles = ((i0 + 31) >> 6) + 1;
    for (int tt = 0; tt < ntiles; ++tt) {
      int jt = tt << 6;
      __syncthreads();
      for (int p = 0; p < 4; ++p) {
        int rr = (t >> 4) + p * 16;
        int c4 = (t & 15) * 4;
        *(float4*)(&Kl[rr][c4]) = *(const float4*)(kT + ((size_t)(b * 64 + rr)) * N_ + jt + c4);
        *(float4*)(&Vl[rr][c4]) =
            *(const float4*)(qkv + ((size_t)(b * N_ + jt + rr)) * QKVN_ + INNER_ + DH_ + c4);
      }
      __syncthreads();
      for (int r = 0; r < 8; ++r) {
        int i = i0 + w * 8 + r;
        int j = jt + lane;
        float s = 0.f;
#pragma unroll 8
        for (int d = 0; d < 64; ++d) s += Ql[w * 8 + r][d] * Kl[d][lane];
        bool valid = (j <= i);
        s = valid ? (s + bias_h[i - j]) : -1e30f;
        float mt = s;
#pragma unroll
        for (int off = 32; off; off >>= 1) mt = fmaxf(mt, __shfl_xor(mt, off));
        float mold = m_s[w][r];
        float mnew = fmaxf(mold, mt);
        float pv = valid ? __expf(s - mnew) : 0.f;
        float corr = __expf(mold - mnew);
        float psum = pv;
#pragma unroll
        for (int off = 32; off; off >>= 1) psum += __shfl_xor(psum, off);
        if (lane == 0) { m_s[w][r] = mnew; l_s[w][r] = l_s[w][r] * corr + psum; }
        ps[w][lane] = pv;  // wave-private LDS: DS ops from one wave complete in order
        float a = accs[w][r][lane] * corr;
#pragma unroll 8
        for (int jj = 0; jj < 64; ++jj) a += ps[w][jj] * Vl[jj][lane];
        accs[w][r][lane] = a;
      }
    }
#pragma unroll
    for (int r = 0; r < 8; ++r) {
      int i = i0 + w * 8 + r;
      float a = accs[w][r][lane];
      o[((size_t)(b * N_ + i)) * INNER_ + h * DH_ + lane] = f2bf(a / l_s[w][r]);
    }
  }
}

extern "C" void kernel_launch(void* const* d_in, const int* in_sizes, int n_in,
                              void* d_out, int out_size, void* d_ws, size_t ws_size,
                              hipStream_t stream) {
  const int*   tok  = (const int*)d_in[0];
  const float* temb = (const float*)d_in[1];
  const float* ln1g = (const float*)d_in[2];
  const float* ln1b = (const float*)d_in[3];
  const float* Wq   = (const float*)d_in[4];
  const float* Wkv  = (const float*)d_in[5];
  const float* Wo   = (const float*)d_in[6];
  const float* bo   = (const float*)d_in[7];
  const float* rel  = (const float*)d_in[8];
  const float* ln2g = (const float*)d_in[9];
  const float* ln2b = (const float*)d_in[10];
  const float* W1   = (const float*)d_in[11];
  const float* b1   = (const float*)d_in[12];
  const float* W2   = (const float*)d_in[13];
  const float* b2   = (const float*)d_in[14];
  const float* lnfg = (const float*)d_in[15];
  const float* lnfb = (const float*)d_in[16];
  const float* Wl   = (const float*)d_in[17];
  const float* bl   = (const float*)d_in[18];
  float* out = (float*)d_out;

  char* p = (char*)d_ws;
  auto carve = [&](size_t bytes) { char* r = p; p += (bytes + 255) & ~(size_t)255; return r; };
  ushort* wtqkv = (ushort*)carve((size_t)DEPTH_ * QKVN_ * DIM_ * 2);
  ushort* wto   = (ushort*)carve((size_t)DEPTH_ * DIM_ * INNER_ * 2);
  ushort* wt1   = (ushort*)carve((size_t)DEPTH_ * FF_ * DIM_ * 2);
  ushort* wt2   = (ushort*)carve((size_t)DEPTH_ * DIM_ * FF_ * 2);
  ushort* wtl   = (ushort*)carve((size_t)VOCAB_ * DIM_ * 2);
  float*  x     = (float*)carve((size_t)M_ * DIM_ * 4);
  ushort* hbuf  = (ushort*)carve((size_t)M_ * DIM_ * 2);
  float*  qkv   = (float*)carve((size_t)M_ * QKVN_ * 4);
  float*  kT    = (float*)carve((size_t)B_ * 64 * N_ * 4);
  ushort* obuf  = (ushort*)carve((size_t)M_ * INNER_ * 2);
  ushort* gbuf  = (ushort*)carve((size_t)M_ * FF_ * 2);
  float*  btab  = (float*)carve((size_t)DEPTH_ * HEADS_ * N_ * 4);

  dim3 tb(32, 8);
  for (int l = 0; l < DEPTH_; ++l) {
    k_transpose_bf16<<<dim3(INNER_ / 32, DIM_ / 32), tb, 0, stream>>>(
        Wq + (size_t)l * DIM_ * INNER_, wtqkv + (size_t)l * QKVN_ * DIM_, DIM_, INNER_);
    k_transpose_bf16<<<dim3(128 / 32, DIM_ / 32), tb, 0, stream>>>(
        Wkv + (size_t)l * DIM_ * 128,
        wtqkv + (size_t)l * QKVN_ * DIM_ + (size_t)INNER_ * DIM_, DIM_, 128);
    k_transpose_bf16<<<dim3(DIM_ / 32, INNER_ / 32), tb, 0, stream>>>(
        Wo + (size_t)l * INNER_ * DIM_, wto + (size_t)l * DIM_ * INNER_, INNER_, DIM_);
    k_transpose_bf16<<<dim3(FF_ / 32, DIM_ / 32), tb, 0, stream>>>(
        W1 + (size_t)l * DIM_ * FF_, wt1 + (size_t)l * FF_ * DIM_, DIM_, FF_);
    k_transpose_bf16<<<dim3(DIM_ / 32, FF_ / 32), tb, 0, stream>>>(
        W2 + (size_t)l * FF_ * DIM_, wt2 + (size_t)l * DIM_ * FF_, FF_, DIM_);
  }
  k_transpose_bf16<<<dim3(VOCAB_ / 32, DIM_ / 32), tb, 0, stream>>>(Wl, wtl, DIM_, VOCAB_);
  k_biastab<<<(DEPTH_ * HEADS_ * N_) / 256, 256, 0, stream>>>(rel, btab);
  k_embed<<<M_, 256, 0, stream>>>(tok, temb, x);

  for (int l = 0; l < DEPTH_; ++l) {
    k_ln<<<M_, 256, 0, stream>>>(x, ln1g + l * DIM_, ln1b + l * DIM_, hbuf);
    k_gemm<0><<<dim3(QKVN_ / 128, M_ / 128), 256, 0, stream>>>(
        hbuf, wtqkv + (size_t)l * QKVN_ * DIM_, nullptr, nullptr, qkv, nullptr,
        M_, QKVN_, DIM_);
    k_kt<<<(B_ * 64 * N_) / 256, 256, 0, stream>>>(qkv, kT);
    k_attn<<<dim3(32, B_ * HEADS_), 256, 0, stream>>>(
        qkv, kT, btab + (size_t)l * HEADS_ * N_, obuf);
    k_gemm<2><<<dim3(DIM_ / 128, M_ / 128), 256, 0, stream>>>(
        obuf, wto + (size_t)l * DIM_ * INNER_, bo + l * DIM_, x, x, nullptr,
        M_, DIM_, INNER_);
    k_ln<<<M_, 256, 0, stream>>>(x, ln2g + l * DIM_, ln2b + l * DIM_, hbuf);
    k_gemm<3><<<dim3(FF_ / 128, M_ / 128), 256, 0, stream>>>(
        hbuf, wt1 + (size_t)l * FF_ * DIM_, b1 + l * FF_, nullptr, nullptr, gbuf,
        M_, FF_, DIM_);
    k_gemm<2><<<dim3(DIM_ / 128, M_ / 128), 256, 0, stream>>>(
        gbuf, wt2 + (size_t)l * DIM_ * FF_, b2 + l * DIM_, x, x, nullptr,
        M_, DIM_, FF_);
  }
  k_ln<<<M_, 256, 0, stream>>>(x, lnfg, lnfb, hbuf);
  k_gemm<1><<<dim3(VOCAB_ / 128, M_ / 128), 256, 0, stream>>>(
      hbuf, wtl, bl, nullptr, out, nullptr, M_, VOCAB_, DIM_);
}

// Round 3
// 2534.756 us; speedup vs baseline: 1.7346x; 1.7346x over previous
//
#include <hip/hip_runtime.h>
#include <math.h>

#define B_ 2
#define N_ 2048
#define DIM_ 1024
#define HEADS_ 8
#define DH_ 64
#define DEPTH_ 4
#define VOCAB_ 32000
#define FF_ 4096
#define INNER_ 512
#define M_ (B_*N_)
#define QKVN_ 640

typedef __bf16 bf16x8 __attribute__((ext_vector_type(8)));
typedef short short8 __attribute__((ext_vector_type(8)));
typedef float f32x4 __attribute__((ext_vector_type(4)));
typedef float f32x16 __attribute__((ext_vector_type(16)));

__device__ __forceinline__ ushort f2bf(float f) {
  union { float f; unsigned u; } v; v.f = f;
  unsigned r = v.u + 0x7fffu + ((v.u >> 16) & 1u);
  return (ushort)(r >> 16);
}

// ---------- transpose fp32 (R,C) -> bf16 (C,R) ----------
__global__ void k_transpose_bf16(const float* __restrict__ in, ushort* __restrict__ out,
                                 int R, int C) {
  __shared__ float tile[32][33];
  int c0 = blockIdx.x * 32, r0 = blockIdx.y * 32;
  int tx = threadIdx.x, ty = threadIdx.y;
  for (int rr = ty; rr < 32; rr += 8)
    tile[rr][tx] = in[(size_t)(r0 + rr) * C + c0 + tx];
  __syncthreads();
  for (int rr = ty; rr < 32; rr += 8)
    out[(size_t)(c0 + rr) * R + r0 + tx] = f2bf(tile[tx][rr]);
}

// ---------- relative-position bias table: [l][h][n] ----------
__global__ void k_biastab(const float* __restrict__ rel_emb, float* __restrict__ tab) {
  int idx = blockIdx.x * 256 + threadIdx.x;
  if (idx >= DEPTH_ * HEADS_ * N_) return;
  int n = idx & (N_ - 1);
  int h = (idx >> 11) & (HEADS_ - 1);
  int l = idx >> 14;
  int bucket;
  if (n < 16) {
    bucket = n;
  } else {
    float nf = (float)n;
    int v = (int)(logf(nf * (1.0f / 16.0f)) / 2.0794415416798357f * 16.0f);
    bucket = 16 + v;
    if (bucket > 31) bucket = 31;
  }
  tab[idx] = rel_emb[(l * 32 + bucket) * HEADS_ + h] * 8.0f;
}

// ---------- embedding ----------
__global__ void k_embed(const int* __restrict__ tok, const float* __restrict__ emb,
                        float* __restrict__ x) {
  int row = blockIdx.x;
  int t = tok[row];
  const float4* src = (const float4*)(emb + (size_t)t * DIM_);
  float4* dst = (float4*)(x + (size_t)row * DIM_);
  dst[threadIdx.x] = src[threadIdx.x];
}

// ---------- layernorm (fp32 in) -> bf16 out ----------
__global__ __launch_bounds__(256) void k_ln(const float* __restrict__ x,
                                            const float* __restrict__ g,
                                            const float* __restrict__ b,
                                            ushort* __restrict__ out) {
  int row = blockIdx.x;
  const float* xr = x + (size_t)row * DIM_;
  int t = threadIdx.x;
  float4 v = *(const float4*)(xr + t * 4);
  float s = v.x + v.y + v.z + v.w;
#pragma unroll
  for (int off = 32; off; off >>= 1) s += __shfl_xor(s, off);
  __shared__ float red[4], red2[4];
  int w = t >> 6;
  if ((t & 63) == 0) red[w] = s;
  __syncthreads();
  float mu = (red[0] + red[1] + red[2] + red[3]) * (1.0f / DIM_);
  float d0 = v.x - mu, d1 = v.y - mu, d2 = v.z - mu, d3 = v.w - mu;
  float sq = d0 * d0 + d1 * d1 + d2 * d2 + d3 * d3;
#pragma unroll
  for (int off = 32; off; off >>= 1) sq += __shfl_xor(sq, off);
  if ((t & 63) == 0) red2[w] = sq;
  __syncthreads();
  float var = (red2[0] + red2[1] + red2[2] + red2[3]) * (1.0f / DIM_);
  float rinv = 1.0f / sqrtf(var + 1e-5f);
  int c = t * 4;
  ushort4 o;
  o.x = f2bf(d0 * rinv * g[c] + b[c]);
  o.y = f2bf(d1 * rinv * g[c + 1] + b[c + 1]);
  o.z = f2bf(d2 * rinv * g[c + 2] + b[c + 2]);
  o.w = f2bf(d3 * rinv * g[c + 3] + b[c + 3]);
  *(ushort4*)(out + (size_t)row * DIM_ + c) = o;
}

// ---------- V transpose (bf16): vT[b][d][n] = qkvb[b,n,576+d] ----------
__global__ void k_vt(const ushort* __restrict__ qkvb, ushort* __restrict__ vT) {
  __shared__ ushort tile[32][33];
  int b = blockIdx.z;
  int d0 = blockIdx.x * 32, n0 = blockIdx.y * 32;
  int tx = threadIdx.x, ty = threadIdx.y;
  for (int rr = ty; rr < 32; rr += 8)
    tile[rr][tx] = qkvb[((size_t)(b * N_ + n0 + rr)) * QKVN_ + INNER_ + DH_ + d0 + tx];
  __syncthreads();
  for (int rr = ty; rr < 32; rr += 8)
    vT[((size_t)(b * 64 + d0 + rr)) * N_ + n0 + tx] = tile[tx][rr];
}

// ---------- GEMM: C[M,N] = A[M,K](bf16) * Bt[N,K](bf16)^T, fp32 acc ----------
// EPI: 0 = Cf=acc; 1 = Cf=acc+bias; 2 = Cf=acc+bias+res (in-place ok);
//      3 = Cb=bf16(gelu(acc+bias)); 4 = Cb=bf16(acc)
template<int EPI>
__global__ __launch_bounds__(256) void k_gemm(const ushort* __restrict__ A,
                                              const ushort* __restrict__ Bt,
                                              const float* __restrict__ bias,
                                              const float* res,
                                              float* Cf, ushort* Cb,
                                              int M, int N, int K) {
  __shared__ ushort As[128][40];
  __shared__ ushort Bs[128][40];
  int t = threadIdx.x;
  int wave = t >> 6, lane = t & 63;
  int wr = (wave >> 1) * 64, wc = (wave & 1) * 64;
  int brow = blockIdx.y * 128, bcol = blockIdx.x * 128;
  int lr = lane & 15, kk = (lane >> 4) * 8;
  f32x4 acc[4][4] = {};

  int sr = t >> 2;
  int sk = (t & 3) * 8;
  const ushort* Ap = A + (size_t)(brow + sr) * K + sk;
  const ushort* Bp = Bt + (size_t)(bcol + sr) * K + sk;

  for (int k0 = 0; k0 < K; k0 += 32) {
    short8 a0 = *(const short8*)Ap;
    short8 a1 = *(const short8*)(Ap + (size_t)64 * K);
    short8 b0 = *(const short8*)Bp;
    short8 b1 = *(const short8*)(Bp + (size_t)64 * K);
    Ap += 32; Bp += 32;
    __syncthreads();
    *(short8*)&As[sr][sk] = a0;
    *(short8*)&As[sr + 64][sk] = a1;
    *(short8*)&Bs[sr][sk] = b0;
    *(short8*)&Bs[sr + 64][sk] = b1;
    __syncthreads();
    bf16x8 af[4], bfv[4];
#pragma unroll
    for (int mi = 0; mi < 4; ++mi)
      af[mi] = __builtin_bit_cast(bf16x8, *(const short8*)&As[wr + mi * 16 + lr][kk]);
#pragma unroll
    for (int ni = 0; ni < 4; ++ni)
      bfv[ni] = __builtin_bit_cast(bf16x8, *(const short8*)&Bs[wc + ni * 16 + lr][kk]);
#pragma unroll
    for (int mi = 0; mi < 4; ++mi)
#pragma unroll
      for (int ni = 0; ni < 4; ++ni)
        acc[mi][ni] = __builtin_amdgcn_mfma_f32_16x16x32_bf16(af[mi], bfv[ni], acc[mi][ni], 0, 0, 0);
  }

  int rbase = brow + wr + ((lane >> 4) << 2);
  int cbase = bcol + wc + lr;
#pragma unroll
  for (int mi = 0; mi < 4; ++mi) {
#pragma unroll
    for (int ni = 0; ni < 4; ++ni) {
      int col = cbase + ni * 16;
      float bv = 0.f;
      if constexpr (EPI == 1 || EPI == 2 || EPI == 3) bv = bias[col];
#pragma unroll
      for (int j = 0; j < 4; ++j) {
        int row = rbase + mi * 16 + j;
        size_t idx = (size_t)row * N + col;
        float v = acc[mi][ni][j];
        if constexpr (EPI == 0) Cf[idx] = v;
        if constexpr (EPI == 1) Cf[idx] = v + bv;
        if constexpr (EPI == 2) Cf[idx] = v + bv + res[idx];
        if constexpr (EPI == 3) {
          float u = v + bv;
          Cb[idx] = f2bf(0.5f * u * (1.0f + erff(u * 0.70710678f)));
        }
        if constexpr (EPI == 4) Cb[idx] = f2bf(v);
      }
    }
  }
}

// ---------- MFMA flash attention ----------
// qkvb: [b][n][640] bf16 (q at h*64, k at 512, v at 576); vT: [b][64][n] bf16.
// grid (16, B*H), 256 threads = 4 waves; wave w handles q-band (4*bx+w)*32..+31.
// Swapped QK^T via mfma_32x32x16: lane owns q = lane&31; S rows kv = crow(r,hi).
__global__ __launch_bounds__(256) void k_attn(const ushort* __restrict__ qkv,
                                              const ushort* __restrict__ vT,
                                              const float* __restrict__ btab,
                                              ushort* __restrict__ o) {
  int bh = blockIdx.y;
  int b = bh >> 3, h = bh & 7;
  int t = threadIdx.x, w = t >> 6, lane = t & 63;
  int hi = lane >> 5, q = lane & 31;
  __shared__ float bias_s[N_];
  __shared__ ushort ot_s[4][32][80];
  {
    const float4* src = (const float4*)(btab + (size_t)h * N_);
    for (int c = t; c < N_ / 4; c += 256) ((float4*)bias_s)[c] = src[c];
  }
  __syncthreads();

  const ushort* qbase = qkv + (size_t)b * N_ * QKVN_;
  int band = blockIdx.x * 4 + w;
  int qb = band * 32;
  int i = qb + q;

  // Q fragments (b-operand: row=q, k=(hi*8 .. +7) within each 16-d chunk)
  bf16x8 qf[4];
#pragma unroll
  for (int dc = 0; dc < 4; ++dc)
    qf[dc] = *(const bf16x8*)(qbase + (size_t)(qb + q) * QKVN_ + h * DH_ + dc * 16 + hi * 8);

  // K fragment prefetch for tile jt=0 (a-operand: row=kv, k-chunk along d)
  bf16x8 kf[4];
#pragma unroll
  for (int dc = 0; dc < 4; ++dc)
    kf[dc] = *(const bf16x8*)(qbase + (size_t)q * QKVN_ + INNER_ + dc * 16 + hi * 8);

  f32x16 oacc0 = {}, oacc1 = {};
  float m_run = -1e30f, l_run = 0.f;

  for (int jt = 0; jt <= qb; jt += 32) {
    // V^T fragments for this tile (a-operand of PV: row=d, k along kv)
    bf16x8 vf[2][2];
#pragma unroll
    for (int dc2 = 0; dc2 < 2; ++dc2)
#pragma unroll
      for (int kc = 0; kc < 2; ++kc)
        vf[dc2][kc] = *(const bf16x8*)(vT + ((size_t)(b * 64 + dc2 * 32 + q)) * N_ +
                                       jt + kc * 16 + hi * 8);
    // S^T = K · Q^T  (C: col=lane&31=q, row=crow(r,hi)=kv_local)
    f32x16 s = {};
#pragma unroll
    for (int dc = 0; dc < 4; ++dc)
      s = __builtin_amdgcn_mfma_f32_32x32x16_bf16(kf[dc], qf[dc], s, 0, 0, 0);
    // prefetch next K tile (latency hidden under softmax)
    if (jt < qb) {
#pragma unroll
      for (int dc = 0; dc < 4; ++dc)
        kf[dc] = *(const bf16x8*)(qbase + (size_t)(jt + 32 + q) * QKVN_ + INNER_ +
                                  dc * 16 + hi * 8);
    }
    // ---- online softmax (per-lane: one q-row; 16 kv values + partner's 16) ----
    float p[16];
    bool diag = (jt == qb);
#pragma unroll
    for (int r = 0; r < 16; ++r) {
      int crow = (r & 3) + 8 * (r >> 2) + 4 * hi;
      int idx = i - jt - crow;
      float sv = 0.125f * s[r] + bias_s[idx & (N_ - 1)];
      p[r] = (diag && idx < 0) ? -1e30f : sv;
    }
    float mt = p[0];
#pragma unroll
    for (int r = 1; r < 16; ++r) mt = fmaxf(mt, p[r]);
    mt = fmaxf(mt, __shfl_xor(mt, 32));
    float mnew = fmaxf(m_run, mt);
    float corr = __expf(m_run - mnew);
    float lsum = 0.f;
#pragma unroll
    for (int r = 0; r < 16; ++r) { p[r] = __expf(p[r] - mnew); lsum += p[r]; }
    lsum += __shfl_xor(lsum, 32);
    l_run = l_run * corr + lsum;
    m_run = mnew;
#pragma unroll
    for (int r = 0; r < 16; ++r) { oacc0[r] *= corr; oacc1[r] *= corr; }
    // ---- pack P to bf16 b-operand fragments (half-exchange with lane^32) ----
    bf16x8 pb[2];
#pragma unroll
    for (int kc = 0; kc < 2; ++kc) {
      int base = 8 * kc;
      unsigned Aw = (unsigned)f2bf(p[base + 4]) | ((unsigned)f2bf(p[base + 5]) << 16);
      unsigned Bw = (unsigned)f2bf(p[base + 6]) | ((unsigned)f2bf(p[base + 7]) << 16);
      unsigned Cw = (unsigned)f2bf(p[base + 0]) | ((unsigned)f2bf(p[base + 1]) << 16);
      unsigned Dw = (unsigned)f2bf(p[base + 2]) | ((unsigned)f2bf(p[base + 3]) << 16);
      unsigned sx = hi ? Cw : Aw, sy = hi ? Dw : Bw;
      unsigned rx = __shfl_xor(sx, 32), ry = __shfl_xor(sy, 32);
      uint4 pk;
      pk.x = hi ? rx : Cw;
      pk.y = hi ? ry : Dw;
      pk.z = hi ? Aw : rx;
      pk.w = hi ? Bw : ry;
      pb[kc] = __builtin_bit_cast(bf16x8, pk);
    }
    // ---- PV: O^T[d][q] += V^T · P ----
    oacc0 = __builtin_amdgcn_mfma_f32_32x32x16_bf16(vf[0][0], pb[0], oacc0, 0, 0, 0);
    oacc0 = __builtin_amdgcn_mfma_f32_32x32x16_bf16(vf[0][1], pb[1], oacc0, 0, 0, 0);
    oacc1 = __builtin_amdgcn_mfma_f32_32x32x16_bf16(vf[1][0], pb[0], oacc1, 0, 0, 0);
    oacc1 = __builtin_amdgcn_mfma_f32_32x32x16_bf16(vf[1][1], pb[1], oacc1, 0, 0, 0);
  }

  // ---- epilogue: O^T -> [q][d] via wave-private LDS, coalesced store ----
  float rl = 1.0f / l_run;
#pragma unroll
  for (int g = 0; g < 4; ++g) {
    ushort4 pk0, pk1;
    pk0.x = f2bf(oacc0[4 * g + 0] * rl); pk0.y = f2bf(oacc0[4 * g + 1] * rl);
    pk0.z = f2bf(oacc0[4 * g + 2] * rl); pk0.w = f2bf(oacc0[4 * g + 3] * rl);
    pk1.x = f2bf(oacc1[4 * g + 0] * rl); pk1.y = f2bf(oacc1[4 * g + 1] * rl);
    pk1.z = f2bf(oacc1[4 * g + 2] * rl); pk1.w = f2bf(oacc1[4 * g + 3] * rl);
    *(ushort4*)&ot_s[w][q][8 * g + 4 * hi] = pk0;
    *(ushort4*)&ot_s[w][q][32 + 8 * g + 4 * hi] = pk1;
  }
  // wave-private LDS: DS ops from one wave complete in order -> no barrier
#pragma unroll
  for (int p4 = 0; p4 < 4; ++p4) {
    int q2 = p4 * 8 + (lane >> 3), doff = (lane & 7) * 8;
    short8 vv = *(const short8*)&ot_s[w][q2][doff];
    *(short8*)(o + ((size_t)(b * N_ + qb + q2)) * INNER_ + h * DH_ + doff) = vv;
  }
}

extern "C" void kernel_launch(void* const* d_in, const int* in_sizes, int n_in,
                              void* d_out, int out_size, void* d_ws, size_t ws_size,
                              hipStream_t stream) {
  const int*   tok  = (const int*)d_in[0];
  const float* temb = (const float*)d_in[1];
  const float* ln1g = (const float*)d_in[2];
  const float* ln1b = (const float*)d_in[3];
  const float* Wq   = (const float*)d_in[4];
  const float* Wkv  = (const float*)d_in[5];
  const float* Wo   = (const float*)d_in[6];
  const float* bo   = (const float*)d_in[7];
  const float* rel  = (const float*)d_in[8];
  const float* ln2g = (const float*)d_in[9];
  const float* ln2b = (const float*)d_in[10];
  const float* W1   = (const float*)d_in[11];
  const float* b1   = (const float*)d_in[12];
  const float* W2   = (const float*)d_in[13];
  const float* b2   = (const float*)d_in[14];
  const float* lnfg = (const float*)d_in[15];
  const float* lnfb = (const float*)d_in[16];
  const float* Wl   = (const float*)d_in[17];
  const float* bl   = (const float*)d_in[18];
  float* out = (float*)d_out;

  char* p = (char*)d_ws;
  auto carve = [&](size_t bytes) { char* r = p; p += (bytes + 255) & ~(size_t)255; return r; };
  ushort* wtqkv = (ushort*)carve((size_t)DEPTH_ * QKVN_ * DIM_ * 2);
  ushort* wto   = (ushort*)carve((size_t)DEPTH_ * DIM_ * INNER_ * 2);
  ushort* wt1   = (ushort*)carve((size_t)DEPTH_ * FF_ * DIM_ * 2);
  ushort* wt2   = (ushort*)carve((size_t)DEPTH_ * DIM_ * FF_ * 2);
  ushort* wtl   = (ushort*)carve((size_t)VOCAB_ * DIM_ * 2);
  float*  x     = (float*)carve((size_t)M_ * DIM_ * 4);
  ushort* hbuf  = (ushort*)carve((size_t)M_ * DIM_ * 2);
  ushort* qkvb  = (ushort*)carve((size_t)M_ * QKVN_ * 2);
  ushort* vT    = (ushort*)carve((size_t)B_ * 64 * N_ * 2);
  ushort* obuf  = (ushort*)carve((size_t)M_ * INNER_ * 2);
  ushort* gbuf  = (ushort*)carve((size_t)M_ * FF_ * 2);
  float*  btab  = (float*)carve((size_t)DEPTH_ * HEADS_ * N_ * 4);

  dim3 tb(32, 8);
  for (int l = 0; l < DEPTH_; ++l) {
    k_transpose_bf16<<<dim3(INNER_ / 32, DIM_ / 32), tb, 0, stream>>>(
        Wq + (size_t)l * DIM_ * INNER_, wtqkv + (size_t)l * QKVN_ * DIM_, DIM_, INNER_);
    k_transpose_bf16<<<dim3(128 / 32, DIM_ / 32), tb, 0, stream>>>(
        Wkv + (size_t)l * DIM_ * 128,
        wtqkv + (size_t)l * QKVN_ * DIM_ + (size_t)INNER_ * DIM_, DIM_, 128);
    k_transpose_bf16<<<dim3(DIM_ / 32, INNER_ / 32), tb, 0, stream>>>(
        Wo + (size_t)l * INNER_ * DIM_, wto + (size_t)l * DIM_ * INNER_, INNER_, DIM_);
    k_transpose_bf16<<<dim3(FF_ / 32, DIM_ / 32), tb, 0, stream>>>(
        W1 + (size_t)l * DIM_ * FF_, wt1 + (size_t)l * FF_ * DIM_, DIM_, FF_);
    k_transpose_bf16<<<dim3(DIM_ / 32, FF_ / 32), tb, 0, stream>>>(
        W2 + (size_t)l * FF_ * DIM_, wt2 + (size_t)l * DIM_ * FF_, FF_, DIM_);
  }
  k_transpose_bf16<<<dim3(VOCAB_ / 32, DIM_ / 32), tb, 0, stream>>>(Wl, wtl, DIM_, VOCAB_);
  k_biastab<<<(DEPTH_ * HEADS_ * N_) / 256, 256, 0, stream>>>(rel, btab);
  k_embed<<<M_, 256, 0, stream>>>(tok, temb, x);

  for (int l = 0; l < DEPTH_; ++l) {
    k_ln<<<M_, 256, 0, stream>>>(x, ln1g + l * DIM_, ln1b + l * DIM_, hbuf);
    k_gemm<4><<<dim3(QKVN_ / 128, M_ / 128), 256, 0, stream>>>(
        hbuf, wtqkv + (size_t)l * QKVN_ * DIM_, nullptr, nullptr, nullptr, qkvb,
        M_, QKVN_, DIM_);
    k_vt<<<dim3(2, 64, B_), tb, 0, stream>>>(qkvb, vT);
    k_attn<<<dim3(16, B_ * HEADS_), 256, 0, stream>>>(
        qkvb, vT, btab + (size_t)l * HEADS_ * N_, obuf);
    k_gemm<2><<<dim3(DIM_ / 128, M_ / 128), 256, 0, stream>>>(
        obuf, wto + (size_t)l * DIM_ * INNER_, bo + l * DIM_, x, x, nullptr,
        M_, DIM_, INNER_);
    k_ln<<<M_, 256, 0, stream>>>(x, ln2g + l * DIM_, ln2b + l * DIM_, hbuf);
    k_gemm<3><<<dim3(FF_ / 128, M_ / 128), 256, 0, stream>>>(
        hbuf, wt1 + (size_t)l * FF_ * DIM_, b1 + l * FF_, nullptr, nullptr, gbuf,
        M_, FF_, DIM_);
    k_gemm<2><<<dim3(DIM_ / 128, M_ / 128), 256, 0, stream>>>(
        gbuf, wt2 + (size_t)l * DIM_ * FF_, b2 + l * DIM_, x, x, nullptr,
        M_, DIM_, FF_);
  }
  k_ln<<<M_, 256, 0, stream>>>(x, lnfg, lnfb, hbuf);
  k_gemm<1><<<dim3(VOCAB_ / 128, M_ / 128), 256, 0, stream>>>(
      hbuf, wtl, bl, nullptr, out, nullptr, M_, VOCAB_, DIM_);
}